// Round 3
// baseline (299.691 us; speedup 1.0000x reference)
//
#include <hip/hip_runtime.h>

#define BATCH 8
#define HH 64
#define WW 64
#define CC 256
#define KK 512
#define CH 7
#define CW 7
#define HW 4096            // HH*WW
#define CROPS_ELEMS (BATCH * KK * CH * CW * CC)   // 51,380,224
#define BOXES_ELEMS (BATCH * KK * 4)              // 16,384
#define INNER_BLKS 6272    // (KK*CH*CW waves per batch) / 4 waves per block

using f4 = __attribute__((ext_vector_type(4))) float;
using f2 = __attribute__((ext_vector_type(2))) float;

// ---------------------------------------------------------------------------
// Kernel 1 (unchanged, stable since round 0): per-batch top-512 by RANK
// SELECTION. key = (ordered_uint(score) << 12) | (4095 - index) is unique per
// element, so rank(i) = #{keys > key_i} is the exact descending-sort position
// with jax.lax.top_k tie semantics (equal score -> lower index first).
// ---------------------------------------------------------------------------
__global__ __launch_bounds__(256) void rank_topk_kernel(
    const float* __restrict__ scores,      // [B, 4096]
    const float* __restrict__ boxes,       // [B, 4096, 4]
    float* __restrict__ boxes_out,         // [B, 512, 4]
    float* __restrict__ idx_out)           // [B, 512] (as float values)
{
    __shared__ unsigned long long keys[HW];   // 32 KB
    __shared__ int cnt[64];

    const int b     = blockIdx.x & 7;         // batch -> XCD
    const int chunk = blockIdx.x >> 3;        // which 64-element slice we rank
    const int tid   = threadIdx.x;

    for (int i = tid; i < HW; i += 256) {
        unsigned int u = __float_as_uint(scores[b * HW + i]);
        u = (u & 0x80000000u) ? ~u : (u | 0x80000000u);
        keys[i] = ((unsigned long long)u << 12) |
                  (unsigned long long)(HW - 1 - i);
    }
    if (tid < 64) cnt[tid] = 0;
    __syncthreads();

    const int e_local = tid & 63;
    const int e       = chunk * 64 + e_local;
    const unsigned long long mine = keys[e];
    const int seg = (tid >> 6) * (HW / 4);

    int c = 0;
    #pragma unroll 8
    for (int j = 0; j < HW / 4; ++j) {
        c += (keys[seg + j] > mine) ? 1 : 0;
    }
    atomicAdd(&cnt[e_local], c);
    __syncthreads();

    if (tid < 64) {
        const int r = cnt[tid];                 // exact descending rank
        if (r < KK) {
            const int i = chunk * 64 + tid;     // original flat index
            idx_out[b * KK + r] = (float)i;
            const float* bp = boxes + (size_t)(b * HW + i) * 4;
            float* op = boxes_out + (size_t)(b * KK + r) * 4;
            op[0] = bp[0]; op[1] = bp[1]; op[2] = bp[2]; op[3] = bp[3];
        }
    }
}

// ---------------------------------------------------------------------------
// Kernel 2 (v4): crop_and_resize — v1 wave-per-pixel structure, CHANNEL-SPLIT
// into two temporally-separated phases.
//
// Theory: the 822 MB poison fill flushes L3+L2 every iteration; each XCD's fm
// slice is EXACTLY 4.0 MiB = exactly its L2 capacity, so with the store
// stream competing, the 822 MB of corner gathers fall to L3/HBM tier
// (~80-120 µs). Halving the channel range per phase halves each XCD's gather
// working set to 2.0 MiB -> truly L2-resident even with the evict-first store
// stream, so gathers run at L2 tier (~24 µs aggregate).
//
// Phase = top bit of the per-batch block index: blocks dispatch in blockIdx
// order, so all lo-channel blocks (all batches) run before hi-channel blocks
// -> the two 2-MiB working sets are separated in time.
//
// Lanes load f2 (8 B) instead of f4: corner gathers are 512 B/wave-instr
// (4 full 128-B lines), stores 512 B contiguous — both fully coalesced.
// Store is the plain NT builtin (v1 semantics — sc1 system-scope regressed).
//
// Coordinate math mirrors the reference's elementwise rounding exactly (no
// FMA contraction): floor() boundaries are discontinuous under the
// clip-after-floor edge semantics.
// ---------------------------------------------------------------------------
__global__ __launch_bounds__(256) void crops_kernel(
    const float* __restrict__ fm,          // [B, 64, 64, 256]
    const float* __restrict__ sboxes,      // [B, 512, 4]
    float* __restrict__ out)               // [B, 512, 7, 7, 256]
{
    const int b     = blockIdx.x & 7;              // batch -> XCD
    const int rest  = blockIdx.x >> 3;             // 0..12543
    const int half  = (rest >= INNER_BLKS) ? 1 : 0; // channel phase
    const int inner = rest - (half ? INNER_BLKS : 0); // 0..6271 within batch
    const int wib   = inner * 4 + (threadIdx.x >> 6);  // wave-in-batch: 0..25087
    const int lane  = threadIdx.x & 63;

    const int q  = wib % 49;               // iy*7 + ix
    const int n  = wib / 49;               // roi within batch
    const int iy = q / 7;
    const int ix = q % 7;
    const int bn = b * KK + n;

    const f4 box = *(const f4*)(sboxes + (size_t)bn * 4);
    const float y1 = box[0], x1 = box[1], y2 = box[2], x2 = box[3];

    const float fy = (float)iy / 6.0f;
    const float fx = (float)ix / 6.0f;
    // y = (y1 + fy*(y2-y1)) * 63 — exact elementwise rounding, no contraction
    const float y = __fmul_rn(__fadd_rn(y1, __fmul_rn(fy, __fsub_rn(y2, y1))), 63.0f);
    const float x = __fmul_rn(__fadd_rn(x1, __fmul_rn(fx, __fsub_rn(x2, x1))), 63.0f);

    const float y0f = floorf(y);
    const float x0f = floorf(x);
    const float wy = y - y0f;
    const float wx = x - x0f;

    int y0 = (int)y0f; y0 = min(max(y0, 0), HH - 1);
    int x0 = (int)x0f; x0 = min(max(x0, 0), WW - 1);
    const int y1i = min(y0 + 1, HH - 1);
    const int x1i = min(x0 + 1, WW - 1);

    const size_t base = (size_t)b * (HH * WW * CC);
    const int c0 = (half << 7) + lane * 2;         // float offset within pixel
    const f2 v00 = *(const f2*)(fm + base + (size_t)(y0  * WW + x0 ) * CC + c0);
    const f2 v01 = *(const f2*)(fm + base + (size_t)(y0  * WW + x1i) * CC + c0);
    const f2 v10 = *(const f2*)(fm + base + (size_t)(y1i * WW + x0 ) * CC + c0);
    const f2 v11 = *(const f2*)(fm + base + (size_t)(y1i * WW + x1i) * CC + c0);

    const float owx = 1.0f - wx;
    const float owy = 1.0f - wy;

    f2 r;
    #pragma unroll
    for (int k = 0; k < 2; ++k) {
        float t  = v00[k] * owx + v01[k] * wx;
        float bo = v10[k] * owx + v11[k] * wx;
        r[k] = t * owy + bo * wy;
    }

    __builtin_nontemporal_store(r, (f2*)(out + (size_t)(bn * 49 + q) * CC + c0));
}

extern "C" void kernel_launch(void* const* d_in, const int* in_sizes, int n_in,
                              void* d_out, int out_size, void* d_ws, size_t ws_size,
                              hipStream_t stream) {
    const float* feature_map = (const float*)d_in[0];   // 8*64*64*256
    const float* boxes       = (const float*)d_in[1];   // 8*64*64*4
    const float* rpn_loss    = (const float*)d_in[2];   // 8*64*64

    float* crops_out = (float*)d_out;                       // 51,380,224
    float* boxes_out = crops_out + CROPS_ELEMS;             // 16,384
    float* idx_out   = boxes_out + BOXES_ELEMS;             // 4,096

    rank_topk_kernel<<<BATCH * 64, 256, 0, stream>>>(rpn_loss, boxes, boxes_out, idx_out);

    // 2 channel phases * 8 batches * 6272 blocks; 4 waves/block, wave = pixel.
    crops_kernel<<<2 * BATCH * INNER_BLKS, 256, 0, stream>>>(feature_map, boxes_out, crops_out);
}

// Round 4
// 271.309 us; speedup vs baseline: 1.1046x; 1.1046x over previous
//
#include <hip/hip_runtime.h>

#define BATCH 8
#define HH 64
#define WW 64
#define CC 256
#define KK 512
#define CH 7
#define CW 7
#define HW 4096            // HH*WW
#define CROPS_ELEMS (BATCH * KK * CH * CW * CC)   // 51,380,224
#define BOXES_ELEMS (BATCH * KK * 4)              // 16,384

using f4 = __attribute__((ext_vector_type(4))) float;

// ---------------------------------------------------------------------------
// Kernel 1 (unchanged, stable since round 0): per-batch top-512 by RANK
// SELECTION. key = (ordered_uint(score) << 12) | (4095 - index) is unique per
// element, so rank(i) = #{keys > key_i} is the exact descending-sort position
// with jax.lax.top_k tie semantics (equal score -> lower index first).
// ---------------------------------------------------------------------------
__global__ __launch_bounds__(256) void rank_topk_kernel(
    const float* __restrict__ scores,      // [B, 4096]
    const float* __restrict__ boxes,       // [B, 4096, 4]
    float* __restrict__ boxes_out,         // [B, 512, 4]
    float* __restrict__ idx_out)           // [B, 512] (as float values)
{
    __shared__ unsigned long long keys[HW];   // 32 KB
    __shared__ int cnt[64];

    const int b     = blockIdx.x & 7;         // batch -> XCD
    const int chunk = blockIdx.x >> 3;        // which 64-element slice we rank
    const int tid   = threadIdx.x;

    for (int i = tid; i < HW; i += 256) {
        unsigned int u = __float_as_uint(scores[b * HW + i]);
        u = (u & 0x80000000u) ? ~u : (u | 0x80000000u);
        keys[i] = ((unsigned long long)u << 12) |
                  (unsigned long long)(HW - 1 - i);
    }
    if (tid < 64) cnt[tid] = 0;
    __syncthreads();

    const int e_local = tid & 63;
    const int e       = chunk * 64 + e_local;
    const unsigned long long mine = keys[e];
    const int seg = (tid >> 6) * (HW / 4);

    int c = 0;
    #pragma unroll 8
    for (int j = 0; j < HW / 4; ++j) {
        c += (keys[seg + j] > mine) ? 1 : 0;
    }
    atomicAdd(&cnt[e_local], c);
    __syncthreads();

    if (tid < 64) {
        const int r = cnt[tid];                 // exact descending rank
        if (r < KK) {
            const int i = chunk * 64 + tid;     // original flat index
            idx_out[b * KK + r] = (float)i;
            const float* bp = boxes + (size_t)(b * HW + i) * 4;
            float* op = boxes_out + (size_t)(b * KK + r) * 4;
            op[0] = bp[0]; op[1] = bp[1]; op[2] = bp[2]; op[3] = bp[3];
        }
    }
}

// ---------------------------------------------------------------------------
// Kernel 2 (v5): crop_and_resize — ONE WAVE PER CROP ROW (n, iy): 7 pixels.
//
// Post-mortem-driven design (rounds 1-3): the three cache-residency
// experiments (sc1 store bypass, channel split) were null/negative, while
// both wave-structure changes moved the time a lot -> the bottleneck is
// per-wave VALU overhead + shallow MLP, not gather cache tier.
//   v1 (wave/pixel): 2 IEEE fdivs (/6.0f is not pow2 -> full div_scale/rcp/
//      fmas/fixup chain) + full coord chain + box load PER PIXEL, 4-load MLP,
//      200,704 waves.
//   v2 (wave/ROI):   right idea, but __launch_bounds__(256,4)'s 128-VGPR cap
//      + 21-entry tables + 28-deep unroll -> scratch spills -> regression.
// v5 middle point, one wave = one (roi, iy) row:
//   - box load + y-chain (incl. its fdiv) amortized over 7 pixels;
//   - x-divisions ELIMINATED: (float)ix/6.0f with constant ix is constant-
//     folded by LLVM at exact IEEE rounding == reference's arange/6 values;
//   - 28 independent corner gathers in flight per wave (vs 4);
//   - 28,672 waves (7x fewer);
//   - __launch_bounds__(256,2): VGPR cap 256 (no spill risk; peak live data
//     ~112 VGPR), >= 8 waves/CU.
// Unchanged vs v1: topk kernel, XCD pinning (batch = blockIdx&7), NT-builtin
// store, elementwise-rounded coordinate math (no FMA contraction -- floor()
// boundaries are discontinuous under clip-after-floor edge semantics).
// ---------------------------------------------------------------------------
__global__ __launch_bounds__(256, 2) void crops_kernel(
    const float* __restrict__ fm,          // [B, 64, 64, 256]
    const float* __restrict__ sboxes,      // [B, 512, 4]
    float* __restrict__ out)               // [B, 512, 7, 7, 256]
{
    const int b     = blockIdx.x & 7;                  // batch -> XCD
    const int inner = blockIdx.x >> 3;                 // 0..895 within batch
    const int wib   = inner * 4 + (threadIdx.x >> 6);  // 0..3583: (n, iy)
    const int lane  = threadIdx.x & 63;

    const int n  = wib / 7;                // roi within batch
    const int iy = wib % 7;                // crop row
    const int bn = b * KK + n;

    const f4 box = *(const f4*)(sboxes + (size_t)bn * 4);
    const float y1 = box[0], x1 = box[1], y2 = box[2], x2 = box[3];

    // y chain: once per wave (the only runtime fdiv left).
    const float fy = (float)iy / 6.0f;
    const float y = __fmul_rn(__fadd_rn(y1, __fmul_rn(fy, __fsub_rn(y2, y1))), 63.0f);
    const float y0f = floorf(y);
    const float wy  = y - y0f;
    const float owy = 1.0f - wy;
    int y0 = (int)y0f; y0 = min(max(y0, 0), HH - 1);
    const int y1i = min(y0 + 1, HH - 1);

    const int c0 = lane * 4;
    const float* fb  = fm + (size_t)b * (HH * WW * CC) + c0;
    const float* py0 = fb + (size_t)y0  * (WW * CC);
    const float* py1 = fb + (size_t)y1i * (WW * CC);
    float* op = out + ((size_t)bn * 49 + iy * 7) * CC + c0;

    const float xd = __fsub_rn(x2, x1);

    #pragma unroll
    for (int ix = 0; ix < CW; ++ix) {
        // fx is a compile-time constant (exact IEEE i/6.0f) after unrolling.
        const float fx = (float)ix / 6.0f;
        const float x = __fmul_rn(__fadd_rn(x1, __fmul_rn(fx, xd)), 63.0f);
        const float x0f = floorf(x);
        const float wx  = x - x0f;
        int x0 = (int)x0f; x0 = min(max(x0, 0), WW - 1);
        const int x1i = min(x0 + 1, WW - 1);

        const f4 v00 = *(const f4*)(py0 + x0  * CC);
        const f4 v01 = *(const f4*)(py0 + x1i * CC);
        const f4 v10 = *(const f4*)(py1 + x0  * CC);
        const f4 v11 = *(const f4*)(py1 + x1i * CC);

        const float owx = 1.0f - wx;
        f4 r;
        #pragma unroll
        for (int k = 0; k < 4; ++k) {
            float t  = v00[k] * owx + v01[k] * wx;
            float bo = v10[k] * owx + v11[k] * wx;
            r[k] = t * owy + bo * wy;
        }
        __builtin_nontemporal_store(r, (f4*)(op + ix * CC));
    }
}

extern "C" void kernel_launch(void* const* d_in, const int* in_sizes, int n_in,
                              void* d_out, int out_size, void* d_ws, size_t ws_size,
                              hipStream_t stream) {
    const float* feature_map = (const float*)d_in[0];   // 8*64*64*256
    const float* boxes       = (const float*)d_in[1];   // 8*64*64*4
    const float* rpn_loss    = (const float*)d_in[2];   // 8*64*64

    float* crops_out = (float*)d_out;                       // 51,380,224
    float* boxes_out = crops_out + CROPS_ELEMS;             // 16,384
    float* idx_out   = boxes_out + BOXES_ELEMS;             // 4,096

    rank_topk_kernel<<<BATCH * 64, 256, 0, stream>>>(rpn_loss, boxes, boxes_out, idx_out);

    // 8 batches * 896 blocks; 4 waves/block; wave = (roi, crop-row).
    const int total_waves = BATCH * KK * CH;                // 28,672
    crops_kernel<<<total_waves / 4, 256, 0, stream>>>(feature_map, boxes_out, crops_out);
}